// Round 3
// baseline (354.845 us; speedup 1.0000x reference)
//
#include <hip/hip_runtime.h>

// SeriesDecompEMA: res = x - ma, ma[t] = beta*ma[t-1] + alpha*x[t], ma[0]=x[0].
// B=64, T=720, C=512 f32. Single-kernel decoupled-lookback chunked scan:
// 1024 one-wave blocks, one per (b, j) chunk (J=16 chunks of L=45 timesteps).
// Ticket ordering guarantees predecessors are scheduled before spinners (no deadlock).
// Phase 1: stream chunk, compute chunk-local partial (seed 0), publish + release flag.
// Phase 2: acquire-spin on j predecessors, Horner carry E_j = sum s_k*(beta^L)^(j-1-k).
// Phase 3: re-scan chunk seeded with E_j (x re-read is L2/L3-hot), write res & ma.

constexpr int kB  = 64;
constexpr int kT  = 720;
constexpr int kC4 = 128;            // float4 groups per row (C = 512)
constexpr int kJ  = 16;             // chunks per sequence
constexpr int kL  = 45;             // chunk length; kJ*kL == kT
constexpr int kNB = kB * kJ;        // 1024 blocks, one wave each

__global__ __launch_bounds__(64) void ema_scan(const float4* __restrict__ x,
                                               const float*  __restrict__ alphap,
                                               float4* __restrict__ res,
                                               float4* __restrict__ ma,
                                               unsigned* __restrict__ flags,   // kNB
                                               unsigned* __restrict__ ticket,  // 1
                                               float4*   __restrict__ s) {     // kNB*kC4
    const int lane = threadIdx.x;

    // ticket-grab: chunks are claimed in (b,j) ascending order, so any block we
    // spin on was claimed earlier -> already scheduled -> forward progress.
    unsigned t = 0;
    if (lane == 0)
        t = __hip_atomic_fetch_add(ticket, 1u, __ATOMIC_RELAXED, __HIP_MEMORY_SCOPE_AGENT);
    t = (unsigned)__shfl((int)t, 0);
    const int b = (int)(t >> 4);
    const int j = (int)(t & 15u);

    const float alpha = alphap[0];
    const float beta  = 1.0f - alpha;
    float betaL = 1.0f;
    #pragma unroll
    for (int i = 0; i < kL; ++i) betaL *= beta;

    const size_t chunk_base = (size_t)(b * kT + j * kL) * kC4;
    const float4* xp = x + chunk_base;
    const int ca = lane, cb = lane + 64;    // each lane owns two c4 columns

    // ---- phase 1: chunk-local partial, seed 0 ----
    const float w0 = (j == 0) ? 1.0f : alpha;   // global t=0 has weight 1
    const float4 ua = xp[ca], ub = xp[cb];
    float pa0 = w0*ua.x, pa1 = w0*ua.y, pa2 = w0*ua.z, pa3 = w0*ua.w;
    float pb0 = w0*ub.x, pb1 = w0*ub.y, pb2 = w0*ub.z, pb3 = w0*ub.w;
    #pragma unroll
    for (int i = 1; i < kL; ++i) {
        const float4 va = xp[i*kC4 + ca];
        const float4 vb = xp[i*kC4 + cb];
        pa0 = fmaf(beta, pa0, alpha*va.x); pa1 = fmaf(beta, pa1, alpha*va.y);
        pa2 = fmaf(beta, pa2, alpha*va.z); pa3 = fmaf(beta, pa3, alpha*va.w);
        pb0 = fmaf(beta, pb0, alpha*vb.x); pb1 = fmaf(beta, pb1, alpha*vb.y);
        pb2 = fmaf(beta, pb2, alpha*vb.z); pb3 = fmaf(beta, pb3, alpha*vb.w);
    }
    float4* sp = s + (size_t)t * kC4;
    sp[ca] = make_float4(pa0, pa1, pa2, pa3);
    sp[cb] = make_float4(pb0, pb1, pb2, pb3);
    if (lane == 0)   // release orders the wave's prior vmem stores before the flag
        __hip_atomic_store(&flags[t], 1u, __ATOMIC_RELEASE, __HIP_MEMORY_SCOPE_AGENT);

    // ---- phase 2: lookback carry E_j (Horner, ascending k) ----
    float Ea0 = 0.f, Ea1 = 0.f, Ea2 = 0.f, Ea3 = 0.f;
    float Eb0 = 0.f, Eb1 = 0.f, Eb2 = 0.f, Eb3 = 0.f;
    const unsigned fb = t & ~15u;           // flag base = b*16
    for (int k = 0; k < j; ++k) {
        while (__hip_atomic_load(&flags[fb + (unsigned)k], __ATOMIC_ACQUIRE,
                                 __HIP_MEMORY_SCOPE_AGENT) == 0u)
            __builtin_amdgcn_s_sleep(8);
        const float4* sk = s + (size_t)(fb + (unsigned)k) * kC4;
        const float4 sa = sk[ca], sb = sk[cb];
        Ea0 = fmaf(Ea0, betaL, sa.x); Ea1 = fmaf(Ea1, betaL, sa.y);
        Ea2 = fmaf(Ea2, betaL, sa.z); Ea3 = fmaf(Ea3, betaL, sa.w);
        Eb0 = fmaf(Eb0, betaL, sb.x); Eb1 = fmaf(Eb1, betaL, sb.y);
        Eb2 = fmaf(Eb2, betaL, sb.z); Eb3 = fmaf(Eb3, betaL, sb.w);
    }

    // ---- phase 3: seeded re-scan, write ma and res ----
    float4* rp = res + chunk_base;
    float4* mp = ma  + chunk_base;
    {   // i = 0 (reuse ua/ub from phase 1); weight 1 only at global t=0 where E==0
        Ea0 = fmaf(beta, Ea0, w0*ua.x); Ea1 = fmaf(beta, Ea1, w0*ua.y);
        Ea2 = fmaf(beta, Ea2, w0*ua.z); Ea3 = fmaf(beta, Ea3, w0*ua.w);
        Eb0 = fmaf(beta, Eb0, w0*ub.x); Eb1 = fmaf(beta, Eb1, w0*ub.y);
        Eb2 = fmaf(beta, Eb2, w0*ub.z); Eb3 = fmaf(beta, Eb3, w0*ub.w);
        mp[ca] = make_float4(Ea0, Ea1, Ea2, Ea3);
        mp[cb] = make_float4(Eb0, Eb1, Eb2, Eb3);
        rp[ca] = make_float4(ua.x-Ea0, ua.y-Ea1, ua.z-Ea2, ua.w-Ea3);
        rp[cb] = make_float4(ub.x-Eb0, ub.y-Eb1, ub.z-Eb2, ub.w-Eb3);
    }
    #pragma unroll
    for (int i = 1; i < kL; ++i) {
        const float4 va = xp[i*kC4 + ca];   // L2/L3-hot (read in phase 1 µs ago)
        const float4 vb = xp[i*kC4 + cb];
        Ea0 = fmaf(beta, Ea0, alpha*va.x); Ea1 = fmaf(beta, Ea1, alpha*va.y);
        Ea2 = fmaf(beta, Ea2, alpha*va.z); Ea3 = fmaf(beta, Ea3, alpha*va.w);
        Eb0 = fmaf(beta, Eb0, alpha*vb.x); Eb1 = fmaf(beta, Eb1, alpha*vb.y);
        Eb2 = fmaf(beta, Eb2, alpha*vb.z); Eb3 = fmaf(beta, Eb3, alpha*vb.w);
        mp[i*kC4 + ca] = make_float4(Ea0, Ea1, Ea2, Ea3);
        mp[i*kC4 + cb] = make_float4(Eb0, Eb1, Eb2, Eb3);
        rp[i*kC4 + ca] = make_float4(va.x-Ea0, va.y-Ea1, va.z-Ea2, va.w-Ea3);
        rp[i*kC4 + cb] = make_float4(vb.x-Eb0, vb.y-Eb1, vb.z-Eb2, vb.w-Eb3);
    }
}

extern "C" void kernel_launch(void* const* d_in, const int* in_sizes, int n_in,
                              void* d_out, int out_size, void* d_ws, size_t ws_size,
                              hipStream_t stream) {
    const float4* x     = (const float4*)d_in[0];
    const float* alphap = (const float*)d_in[1];
    float4* res = (float4*)d_out;                       // outputs: res then ma, flat
    float4* ma  = res + (size_t)kB * kT * kC4;

    // ws layout: [flags: kNB u32][ticket: u32][pad to 8 KiB][s: kNB*kC4 float4]
    unsigned* flags  = (unsigned*)d_ws;
    unsigned* ticket = flags + kNB;
    float4*   s      = (float4*)((char*)d_ws + 8192);

    hipMemsetAsync(d_ws, 0, 8192, stream);              // zero flags + ticket
    ema_scan<<<kNB, 64, 0, stream>>>(x, alphap, res, ma, flags, ticket, s);
}